// Round 1
// baseline (11358.331 us; speedup 1.0000x reference)
//
#include <hip/hip_runtime.h>
#include <math.h>

#define N_NODES 100000
#define N_EDGES 1600000
#define DIM     128
#define NCLS    64
#define ALPHA   0.1f

// ---------------- hi = ALPHA * h0 (elementwise, float4) ----------------
__global__ void k_scale(const float* __restrict__ h0, float* __restrict__ hi, int n4) {
    int i = blockIdx.x * blockDim.x + threadIdx.x;
    if (i < n4) {
        float4 v = ((const float4*)h0)[i];
        v.x *= ALPHA; v.y *= ALPHA; v.z *= ALPHA; v.w *= ALPHA;
        ((float4*)hi)[i] = v;
    }
}

// ---------------- SpMM scatter: hi[dst] += (1-ALPHA)*w*h[src] ----------------
// 32 threads per edge, 4 dims (float4) per thread.
__global__ void k_spmm(const int* __restrict__ src, const int* __restrict__ dst,
                       const float* __restrict__ ew, const float* __restrict__ h,
                       float* __restrict__ hi) {
    int t = blockIdx.x * blockDim.x + threadIdx.x;
    int e = t >> 5;
    if (e >= N_EDGES) return;
    int d4 = (t & 31) << 2;
    int s = src[e], d = dst[e];
    float w = (1.0f - ALPHA) * ew[e];
    float4 v = *(const float4*)(h + (size_t)s * DIM + d4);
    float* o = hi + (size_t)d * DIM + d4;
    unsafeAtomicAdd(o + 0, w * v.x);
    unsafeAtomicAdd(o + 1, w * v.y);
    unsafeAtomicAdd(o + 2, w * v.z);
    unsafeAtomicAdd(o + 3, w * v.w);
}

// ---------------- input GEMM: h0 = relu(x @ W_in + b) ----------------
// W (128x128 fp32, 64KB) in LDS; each wave processes 8 rows; lane owns cols 2l,2l+1.
#define RPW 8                      // rows per wave
#define RPB 32                     // rows per block (4 waves)

__global__ __launch_bounds__(256, 2) void k_in(
    const float* __restrict__ x, const float* __restrict__ W,
    const float* __restrict__ b, float* __restrict__ h0) {
    __shared__ float sW[DIM * DIM];
    __shared__ float srow[RPB][DIM];
    int tid = threadIdx.x;
    int wave = tid >> 6, lane = tid & 63;
    int w8 = wave * RPW;
    for (int i = tid; i < DIM * DIM / 4; i += 256)
        ((float4*)sW)[i] = ((const float4*)W)[i];
    __syncthreads();
    float2 bv = ((const float2*)b)[lane];

    for (int base = blockIdx.x * RPB; base < N_NODES; base += gridDim.x * RPB) {
        int r0 = base + w8;
        #pragma unroll
        for (int i = 0; i < RPW; i++) {
            int row = r0 + i;
            float2 v = (row < N_NODES) ? ((const float2*)(x + (size_t)row * DIM))[lane]
                                       : make_float2(0.f, 0.f);
            ((float2*)srow[w8 + i])[lane] = v;
        }
        float2 acc[RPW];
        #pragma unroll
        for (int i = 0; i < RPW; i++) acc[i] = make_float2(0.f, 0.f);
        #pragma unroll 4
        for (int k = 0; k < DIM; k++) {
            float2 wv = ((const float2*)(sW + k * DIM))[lane];
            #pragma unroll
            for (int i = 0; i < RPW; i++) {
                float xv = srow[w8 + i][k];
                acc[i].x += xv * wv.x;
                acc[i].y += xv * wv.y;
            }
        }
        #pragma unroll
        for (int i = 0; i < RPW; i++) {
            int row = r0 + i;
            if (row < N_NODES) {
                float ox = fmaxf(acc[i].x + bv.x, 0.f);
                float oy = fmaxf(acc[i].y + bv.y, 0.f);
                ((float2*)(h0 + (size_t)row * DIM))[lane] = make_float2(ox, oy);
            }
        }
    }
}

// ---------------- layer GEMM: h = relu(theta*(s@W) + (1-theta)*s + hprev) ----------------
__global__ __launch_bounds__(256, 2) void k_layer(
    const float* __restrict__ s_in, const float* __restrict__ hprev,
    const float* __restrict__ W, float* __restrict__ hout, float theta) {
    __shared__ float sW[DIM * DIM];
    __shared__ float srow[RPB][DIM];
    int tid = threadIdx.x;
    int wave = tid >> 6, lane = tid & 63;
    int w8 = wave * RPW;
    for (int i = tid; i < DIM * DIM / 4; i += 256)
        ((float4*)sW)[i] = ((const float4*)W)[i];
    __syncthreads();
    float omt = 1.f - theta;

    for (int base = blockIdx.x * RPB; base < N_NODES; base += gridDim.x * RPB) {
        int r0 = base + w8;
        float2 sv[RPW];
        #pragma unroll
        for (int i = 0; i < RPW; i++) {
            int row = r0 + i;
            float2 v = (row < N_NODES) ? ((const float2*)(s_in + (size_t)row * DIM))[lane]
                                       : make_float2(0.f, 0.f);
            sv[i] = v;
            ((float2*)srow[w8 + i])[lane] = v;
        }
        float2 acc[RPW];
        #pragma unroll
        for (int i = 0; i < RPW; i++) acc[i] = make_float2(0.f, 0.f);
        #pragma unroll 4
        for (int k = 0; k < DIM; k++) {
            float2 wv = ((const float2*)(sW + k * DIM))[lane];
            #pragma unroll
            for (int i = 0; i < RPW; i++) {
                float xv = srow[w8 + i][k];
                acc[i].x += xv * wv.x;
                acc[i].y += xv * wv.y;
            }
        }
        #pragma unroll
        for (int i = 0; i < RPW; i++) {
            int row = r0 + i;
            if (row < N_NODES) {
                float2 hp = ((const float2*)(hprev + (size_t)row * DIM))[lane];
                float ox = theta * acc[i].x + omt * sv[i].x + hp.x;
                float oy = theta * acc[i].y + omt * sv[i].y + hp.y;
                ((float2*)(hout + (size_t)row * DIM))[lane] =
                    make_float2(fmaxf(ox, 0.f), fmaxf(oy, 0.f));
            }
        }
    }
}

// ---------------- output: log_softmax(h @ W_out + b_out) ----------------
// one wave per row; lane = class column (C=64).
__global__ __launch_bounds__(256, 2) void k_out(
    const float* __restrict__ h, const float* __restrict__ Wo,
    const float* __restrict__ bo, float* __restrict__ out) {
    __shared__ float sW[DIM * NCLS];
    __shared__ float srow[4][DIM];
    int tid = threadIdx.x, wave = tid >> 6, lane = tid & 63;
    for (int i = tid; i < DIM * NCLS / 4; i += 256)
        ((float4*)sW)[i] = ((const float4*)Wo)[i];
    __syncthreads();
    int row = blockIdx.x * 4 + wave;
    if (row >= N_NODES) return;
    ((float2*)srow[wave])[lane] = ((const float2*)(h + (size_t)row * DIM))[lane];
    float acc = bo[lane];
    #pragma unroll 4
    for (int k = 0; k < DIM; k++)
        acc += srow[wave][k] * sW[k * NCLS + lane];
    float m = acc;
    #pragma unroll
    for (int off = 32; off; off >>= 1) m = fmaxf(m, __shfl_xor(m, off));
    float ex = __expf(acc - m);
    float s = ex;
    #pragma unroll
    for (int off = 32; off; off >>= 1) s += __shfl_xor(s, off);
    out[(size_t)row * NCLS + lane] = acc - m - logf(s);
}

extern "C" void kernel_launch(void* const* d_in, const int* in_sizes, int n_in,
                              void* d_out, int out_size, void* d_ws, size_t ws_size,
                              hipStream_t stream) {
    const float* x    = (const float*)d_in[0];
    const int*   esrc = (const int*)d_in[1];
    const int*   edst = (const int*)d_in[2];
    const float* ew   = (const float*)d_in[3];
    const float* w_in = (const float*)d_in[4];
    const float* b_in = (const float*)d_in[5];
    const float* gcnw = (const float*)d_in[6];   // [4,128,128]
    const float* wout = (const float*)d_in[7];
    const float* bout = (const float*)d_in[8];
    float* out = (float*)d_out;

    float* ws = (float*)d_ws;
    float* h0 = ws;                          // 12.8M floats
    float* h  = ws + (size_t)N_NODES * DIM;  // 12.8M floats
    float* hi = h  + (size_t)N_NODES * DIM;  // 12.8M floats

    const int n4 = N_NODES * DIM / 4;
    const int GEMM_BLOCKS = 512;
    const int SPMM_BLOCKS = (N_EDGES * 32 + 255) / 256;

    // h0 = relu(x @ w_in + b_in)
    k_in<<<GEMM_BLOCKS, 256, 0, stream>>>(x, w_in, b_in, h0);

    const float* hprev = h0;
    for (int l = 0; l < 4; l++) {
        float theta = logf(0.5f / (float)(l + 2) + 1.0f);
        // hi = ALPHA*h0
        k_scale<<<(n4 + 255) / 256, 256, 0, stream>>>(h0, hi, n4);
        // hi += (1-ALPHA)*w*hprev[src]   (scatter into dst rows)
        k_spmm<<<SPMM_BLOCKS, 256, 0, stream>>>(esrc, edst, ew, hprev, hi);
        // h = relu(theta*(hi@W_l) + (1-theta)*hi + hprev)
        k_layer<<<GEMM_BLOCKS, 256, 0, stream>>>(hi, hprev, gcnw + (size_t)l * DIM * DIM,
                                                 h, theta);
        hprev = h;
    }

    // out = log_softmax(h @ w_out + b_out)
    k_out<<<(N_NODES + 3) / 4, 256, 0, stream>>>(h, wout, bout, out);
}

// Round 2
// 1518.204 us; speedup vs baseline: 7.4814x; 7.4814x over previous
//
#include <hip/hip_runtime.h>
#include <math.h>

#define N_NODES 100000
#define N_EDGES 1600000
#define DIM     128
#define NCLS    64
#define ALPHA   0.1f

// ================= CSR build (counting sort by dst) =================

__global__ void k_count(const int* __restrict__ dst, int* __restrict__ deg) {
    int e = blockIdx.x * blockDim.x + threadIdx.x;
    if (e < N_EDGES) atomicAdd(&deg[dst[e]], 1);
}

// single-block exclusive scan of deg[0..N) -> row_ptr, cursor; row_ptr[N]=E
__global__ __launch_bounds__(1024) void k_scan(const int* __restrict__ deg,
                                               int* __restrict__ row_ptr,
                                               int* __restrict__ cursor) {
    __shared__ int part[1024];
    int t = threadIdx.x;
    const int CH = (N_NODES + 1023) / 1024;   // 98
    int lo = t * CH, hi = min(lo + CH, N_NODES);
    int s = 0;
    for (int i = lo; i < hi; i++) s += deg[i];
    part[t] = s;
    __syncthreads();
    for (int off = 1; off < 1024; off <<= 1) {
        int v = (t >= off) ? part[t - off] : 0;
        __syncthreads();
        part[t] += v;
        __syncthreads();
    }
    int base = (t > 0) ? part[t - 1] : 0;
    for (int i = lo; i < hi; i++) {
        int d = deg[i];
        row_ptr[i] = base;
        cursor[i] = base;
        base += d;
    }
    if (t == 1023) row_ptr[N_NODES] = part[1023];
}

// colw[pos] = (src, (1-ALPHA)*w) packed
__global__ void k_scatter(const int* __restrict__ src, const int* __restrict__ dst,
                          const float* __restrict__ ew, int* __restrict__ cursor,
                          int2* __restrict__ colw) {
    int e = blockIdx.x * blockDim.x + threadIdx.x;
    if (e >= N_EDGES) return;
    int d = dst[e];
    int pos = atomicAdd(&cursor[d], 1);
    colw[pos] = make_int2(src[e], __float_as_int((1.0f - ALPHA) * ew[e]));
}

// ================= SpMM gather: out[i] = ALPHA*h0[i] + sum_e w*h[src] =================
// one wave per dst node; lane owns 2 dims (float2).
__global__ __launch_bounds__(256, 4) void k_spmm_csr(
    const int* __restrict__ row_ptr, const int2* __restrict__ colw,
    const float* __restrict__ h, const float* __restrict__ h0,
    float* __restrict__ out) {
    int node = blockIdx.x * 4 + (threadIdx.x >> 6);
    if (node >= N_NODES) return;
    int lane = threadIdx.x & 63;
    int beg = row_ptr[node], end = row_ptr[node + 1];

    float2 z = ((const float2*)(h0 + (size_t)node * DIM))[lane];
    float2 acc = make_float2(ALPHA * z.x, ALPHA * z.y);

    int e = beg;
    for (; e + 1 < end; e += 2) {
        int2 c0 = colw[e];
        int2 c1 = colw[e + 1];
        float2 v0 = ((const float2*)(h + (size_t)c0.x * DIM))[lane];
        float2 v1 = ((const float2*)(h + (size_t)c1.x * DIM))[lane];
        float w0 = __int_as_float(c0.y), w1 = __int_as_float(c1.y);
        acc.x += w0 * v0.x + w1 * v1.x;
        acc.y += w0 * v0.y + w1 * v1.y;
    }
    if (e < end) {
        int2 c0 = colw[e];
        float2 v0 = ((const float2*)(h + (size_t)c0.x * DIM))[lane];
        float w0 = __int_as_float(c0.y);
        acc.x += w0 * v0.x;
        acc.y += w0 * v0.y;
    }
    ((float2*)(out + (size_t)node * DIM))[lane] = acc;
}

// ================= input GEMM: h0 = relu(x @ W_in + b) =================
#define RPW 8
#define RPB 32

__global__ __launch_bounds__(256, 2) void k_in(
    const float* __restrict__ x, const float* __restrict__ W,
    const float* __restrict__ b, float* __restrict__ h0) {
    __shared__ float sW[DIM * DIM];
    __shared__ float srow[RPB][DIM];
    int tid = threadIdx.x;
    int wave = tid >> 6, lane = tid & 63;
    int w8 = wave * RPW;
    for (int i = tid; i < DIM * DIM / 4; i += 256)
        ((float4*)sW)[i] = ((const float4*)W)[i];
    __syncthreads();
    float2 bv = ((const float2*)b)[lane];

    for (int base = blockIdx.x * RPB; base < N_NODES; base += gridDim.x * RPB) {
        int r0 = base + w8;
        #pragma unroll
        for (int i = 0; i < RPW; i++) {
            int row = r0 + i;
            float2 v = (row < N_NODES) ? ((const float2*)(x + (size_t)row * DIM))[lane]
                                       : make_float2(0.f, 0.f);
            ((float2*)srow[w8 + i])[lane] = v;
        }
        float2 acc[RPW];
        #pragma unroll
        for (int i = 0; i < RPW; i++) acc[i] = make_float2(0.f, 0.f);
        #pragma unroll 4
        for (int k = 0; k < DIM; k++) {
            float2 wv = ((const float2*)(sW + k * DIM))[lane];
            #pragma unroll
            for (int i = 0; i < RPW; i++) {
                float xv = srow[w8 + i][k];
                acc[i].x += xv * wv.x;
                acc[i].y += xv * wv.y;
            }
        }
        #pragma unroll
        for (int i = 0; i < RPW; i++) {
            int row = r0 + i;
            if (row < N_NODES) {
                float ox = fmaxf(acc[i].x + bv.x, 0.f);
                float oy = fmaxf(acc[i].y + bv.y, 0.f);
                ((float2*)(h0 + (size_t)row * DIM))[lane] = make_float2(ox, oy);
            }
        }
    }
}

// ========== layer GEMM: h = relu(theta*(s@W) + (1-theta)*s + hprev) ==========
__global__ __launch_bounds__(256, 2) void k_layer(
    const float* __restrict__ s_in, const float* __restrict__ hprev,
    const float* __restrict__ W, float* __restrict__ hout, float theta) {
    __shared__ float sW[DIM * DIM];
    __shared__ float srow[RPB][DIM];
    int tid = threadIdx.x;
    int wave = tid >> 6, lane = tid & 63;
    int w8 = wave * RPW;
    for (int i = tid; i < DIM * DIM / 4; i += 256)
        ((float4*)sW)[i] = ((const float4*)W)[i];
    __syncthreads();
    float omt = 1.f - theta;

    for (int base = blockIdx.x * RPB; base < N_NODES; base += gridDim.x * RPB) {
        int r0 = base + w8;
        float2 sv[RPW];
        #pragma unroll
        for (int i = 0; i < RPW; i++) {
            int row = r0 + i;
            float2 v = (row < N_NODES) ? ((const float2*)(s_in + (size_t)row * DIM))[lane]
                                       : make_float2(0.f, 0.f);
            sv[i] = v;
            ((float2*)srow[w8 + i])[lane] = v;
        }
        float2 acc[RPW];
        #pragma unroll
        for (int i = 0; i < RPW; i++) acc[i] = make_float2(0.f, 0.f);
        #pragma unroll 4
        for (int k = 0; k < DIM; k++) {
            float2 wv = ((const float2*)(sW + k * DIM))[lane];
            #pragma unroll
            for (int i = 0; i < RPW; i++) {
                float xv = srow[w8 + i][k];
                acc[i].x += xv * wv.x;
                acc[i].y += xv * wv.y;
            }
        }
        #pragma unroll
        for (int i = 0; i < RPW; i++) {
            int row = r0 + i;
            if (row < N_NODES) {
                float2 hp = ((const float2*)(hprev + (size_t)row * DIM))[lane];
                float ox = theta * acc[i].x + omt * sv[i].x + hp.x;
                float oy = theta * acc[i].y + omt * sv[i].y + hp.y;
                ((float2*)(hout + (size_t)row * DIM))[lane] =
                    make_float2(fmaxf(ox, 0.f), fmaxf(oy, 0.f));
            }
        }
    }
}

// ================= output: log_softmax(h @ W_out + b_out) =================
__global__ __launch_bounds__(256, 2) void k_out(
    const float* __restrict__ h, const float* __restrict__ Wo,
    const float* __restrict__ bo, float* __restrict__ out) {
    __shared__ float sW[DIM * NCLS];
    __shared__ float srow[4][DIM];
    int tid = threadIdx.x, wave = tid >> 6, lane = tid & 63;
    for (int i = tid; i < DIM * NCLS / 4; i += 256)
        ((float4*)sW)[i] = ((const float4*)Wo)[i];
    __syncthreads();
    int row = blockIdx.x * 4 + wave;
    if (row >= N_NODES) return;
    ((float2*)srow[wave])[lane] = ((const float2*)(h + (size_t)row * DIM))[lane];
    float acc = bo[lane];
    #pragma unroll 4
    for (int k = 0; k < DIM; k++)
        acc += srow[wave][k] * sW[k * NCLS + lane];
    float m = acc;
    #pragma unroll
    for (int off = 32; off; off >>= 1) m = fmaxf(m, __shfl_xor(m, off));
    float ex = __expf(acc - m);
    float s = ex;
    #pragma unroll
    for (int off = 32; off; off >>= 1) s += __shfl_xor(s, off);
    out[(size_t)row * NCLS + lane] = acc - m - logf(s);
}

extern "C" void kernel_launch(void* const* d_in, const int* in_sizes, int n_in,
                              void* d_out, int out_size, void* d_ws, size_t ws_size,
                              hipStream_t stream) {
    const float* x    = (const float*)d_in[0];
    const int*   esrc = (const int*)d_in[1];
    const int*   edst = (const int*)d_in[2];
    const float* ew   = (const float*)d_in[3];
    const float* w_in = (const float*)d_in[4];
    const float* b_in = (const float*)d_in[5];
    const float* gcnw = (const float*)d_in[6];   // [4,128,128]
    const float* wout = (const float*)d_in[7];
    const float* bout = (const float*)d_in[8];
    float* out = (float*)d_out;

    // workspace layout (floats/ints, 4B units)
    float* ws = (float*)d_ws;
    float* h0   = ws;                                  // 12.8M floats
    float* h    = h0 + (size_t)N_NODES * DIM;          // 12.8M
    float* hi   = h  + (size_t)N_NODES * DIM;          // 12.8M
    int2*  colw = (int2*)(hi + (size_t)N_NODES * DIM); // 1.6M int2 (even offset)
    int*   row_ptr = (int*)(colw + N_EDGES);           // N+1 ints
    int*   cursor  = row_ptr + (N_NODES + 1);          // N ints
    int*   deg     = cursor + N_NODES;                 // N ints

    const int EB = (N_EDGES + 255) / 256;
    const int GEMM_BLOCKS = 512;

    // ---- CSR build (once per call) ----
    hipMemsetAsync(deg, 0, N_NODES * sizeof(int), stream);
    k_count<<<EB, 256, 0, stream>>>(edst, deg);
    k_scan<<<1, 1024, 0, stream>>>(deg, row_ptr, cursor);
    k_scatter<<<EB, 256, 0, stream>>>(esrc, edst, ew, cursor, colw);

    // h0 = relu(x @ w_in + b_in)
    k_in<<<GEMM_BLOCKS, 256, 0, stream>>>(x, w_in, b_in, h0);

    const float* hprev = h0;
    for (int l = 0; l < 4; l++) {
        float theta = logf(0.5f / (float)(l + 2) + 1.0f);
        // hi = ALPHA*h0 + sum_e (1-ALPHA)*w*hprev[src]   (pure gather, no atomics)
        k_spmm_csr<<<(N_NODES + 3) / 4, 256, 0, stream>>>(row_ptr, colw, hprev, h0, hi);
        // h = relu(theta*(hi@W_l) + (1-theta)*hi + hprev)
        k_layer<<<GEMM_BLOCKS, 256, 0, stream>>>(hi, hprev, gcnw + (size_t)l * DIM * DIM,
                                                 h, theta);
        hprev = h;
    }

    // out = log_softmax(h @ w_out + b_out)
    k_out<<<(N_NODES + 3) / 4, 256, 0, stream>>>(h, wout, bout, out);
}